// Round 2
// baseline (14172.659 us; speedup 1.0000x reference)
//
#include <hip/hip_runtime.h>
#include <math.h>

#define QKVLD 1536

// ---------------- LayerNorm with front zero-padding ----------------
__global__ __launch_bounds__(256) void ln_pad_kernel(
    const float* __restrict__ src1, int n1,
    const float* __restrict__ src2,
    const float* __restrict__ w, const float* __restrict__ b,
    float* __restrict__ h, int pad)
{
    int r = blockIdx.x;
    int tid = threadIdx.x;
    float* out = h + (size_t)r * 512;
    if (r < pad) { out[tid] = 0.f; out[tid + 256] = 0.f; return; }
    int i = r - pad;
    const float* src = (i < n1) ? (src1 + (size_t)i * 512)
                                : (src2 + (size_t)(i - n1) * 512);
    float x0 = src[tid], x1 = src[tid + 256];
    float s = x0 + x1, sq = x0 * x0 + x1 * x1;
#pragma unroll
    for (int o = 32; o >= 1; o >>= 1) { s += __shfl_xor(s, o); sq += __shfl_xor(sq, o); }
    __shared__ float rs[4], rq[4];
    int wid = tid >> 6, lane = tid & 63;
    if (lane == 0) { rs[wid] = s; rq[wid] = sq; }
    __syncthreads();
    s = rs[0] + rs[1] + rs[2] + rs[3];
    sq = rq[0] + rq[1] + rq[2] + rq[3];
    float mu = s * (1.f / 512.f);
    float var = sq * (1.f / 512.f) - mu * mu;
    float inv = rsqrtf(var + 1e-5f);
    out[tid]       = (x0 - mu) * inv * w[tid] + b[tid];
    out[tid + 256] = (x1 - mu) * inv * w[tid + 256] + b[tid + 256];
}

// ---------------- GEMM C[M x Nc] = A[M x K] @ B[Nc x K]^T, 128x128 tile, 8x8/thread ----
// optional epilogue: C = acc + omega[0]*resid + bias (resid row-stride = ldc)
__global__ __launch_bounds__(256) void gemm_nt128(
    const float* __restrict__ A, const float* __restrict__ B, float* __restrict__ C,
    int K, int lda, int ldb, int ldc,
    const float* __restrict__ resid, const float* __restrict__ bias,
    const float* __restrict__ omega)
{
    __shared__ __align__(16) float As[16][128];
    __shared__ __align__(16) float Bs[16][128];
    int tid = threadIdx.x;
    int tx = tid & 15, ty = tid >> 4;
    int row0 = blockIdx.x * 128, col0 = blockIdx.y * 128;
    int lr = tid >> 1, lk = (tid & 1) << 3;   // each thread: 1 row, 8 consecutive k
    const float* Ap = A + (size_t)(row0 + lr) * lda + lk;
    const float* Bp = B + (size_t)(col0 + lr) * ldb + lk;
    float acc[8][8] = {};
    float4 a0 = *(const float4*)(Ap);
    float4 a1 = *(const float4*)(Ap + 4);
    float4 b0 = *(const float4*)(Bp);
    float4 b1 = *(const float4*)(Bp + 4);
    for (int kt = 0; kt < K; kt += 16) {
        __syncthreads();
        As[lk + 0][lr] = a0.x; As[lk + 1][lr] = a0.y; As[lk + 2][lr] = a0.z; As[lk + 3][lr] = a0.w;
        As[lk + 4][lr] = a1.x; As[lk + 5][lr] = a1.y; As[lk + 6][lr] = a1.z; As[lk + 7][lr] = a1.w;
        Bs[lk + 0][lr] = b0.x; Bs[lk + 1][lr] = b0.y; Bs[lk + 2][lr] = b0.z; Bs[lk + 3][lr] = b0.w;
        Bs[lk + 4][lr] = b1.x; Bs[lk + 5][lr] = b1.y; Bs[lk + 6][lr] = b1.z; Bs[lk + 7][lr] = b1.w;
        __syncthreads();
        if (kt + 16 < K) {
            a0 = *(const float4*)(Ap + kt + 16); a1 = *(const float4*)(Ap + kt + 20);
            b0 = *(const float4*)(Bp + kt + 16); b1 = *(const float4*)(Bp + kt + 20);
        }
#pragma unroll
        for (int k = 0; k < 16; ++k) {
            float4 av0 = *(const float4*)(&As[k][ty << 2]);
            float4 av1 = *(const float4*)(&As[k][64 + (ty << 2)]);
            float4 bv0 = *(const float4*)(&Bs[k][tx << 2]);
            float4 bv1 = *(const float4*)(&Bs[k][64 + (tx << 2)]);
            float a[8] = {av0.x, av0.y, av0.z, av0.w, av1.x, av1.y, av1.z, av1.w};
            float bb[8] = {bv0.x, bv0.y, bv0.z, bv0.w, bv1.x, bv1.y, bv1.z, bv1.w};
#pragma unroll
            for (int i = 0; i < 8; ++i)
#pragma unroll
                for (int j = 0; j < 8; ++j) acc[i][j] += a[i] * bb[j];
        }
    }
#pragma unroll
    for (int ih = 0; ih < 2; ++ih)
#pragma unroll
    for (int i = 0; i < 4; ++i) {
        int r = row0 + ih * 64 + (ty << 2) + i;
#pragma unroll
        for (int jh = 0; jh < 2; ++jh) {
            int c = col0 + jh * 64 + (tx << 2);
            float4 o = make_float4(acc[ih * 4 + i][jh * 4 + 0], acc[ih * 4 + i][jh * 4 + 1],
                                   acc[ih * 4 + i][jh * 4 + 2], acc[ih * 4 + i][jh * 4 + 3]);
            if (resid) {
                float om = omega[0];
                float4 rv = *(const float4*)(resid + (size_t)r * ldc + c);
                float4 bv = *(const float4*)(bias + c);
                o.x += om * rv.x + bv.x; o.y += om * rv.y + bv.y;
                o.z += om * rv.z + bv.z; o.w += om * rv.w + bv.w;
            }
            *(float4*)(C + (size_t)r * ldc + c) = o;
        }
    }
}

// ---------------- landmark means (q_l, k_l) ----------------
__global__ __launch_bounds__(256) void landmarks_kernel(
    const float* __restrict__ qkv, float* __restrict__ ql, float* __restrict__ kl, int l)
{
    int j = blockIdx.x;
    int tid = threadIdx.x;
    float inv = 1.f / (float)l;
    const float* base = qkv + (size_t)j * l * QKVLD;
    float sq0 = 0, sq1 = 0, sk0 = 0, sk1 = 0;
    for (int r = 0; r < l; ++r) {
        const float* row = base + (size_t)r * QKVLD;
        sq0 += row[tid]; sq1 += row[tid + 256];
        sk0 += row[512 + tid]; sk1 += row[512 + tid + 256];
    }
    ql[j * 512 + tid] = sq0 * inv; ql[j * 512 + tid + 256] = sq1 * inv;
    kl[j * 512 + tid] = sk0 * inv; kl[j * 512 + tid + 256] = sk1 * inv;
}

// ---------------- attn2 = softmax(0.125 * q_l @ k_l^T) per head ----------------
__global__ __launch_bounds__(256) void attn2_kernel(
    const float* __restrict__ ql, const float* __restrict__ kl, float* __restrict__ a2)
{
    int hh = blockIdx.y, i = blockIdx.x;
    int tid = threadIdx.x;
    __shared__ float qrow[64];
    __shared__ float red[4], red2[4];
    if (tid < 64) qrow[tid] = 0.125f * ql[i * 512 + hh * 64 + tid];
    __syncthreads();
    const float* krow = kl + (size_t)tid * 512 + hh * 64;
    float sc = 0.f;
#pragma unroll
    for (int d = 0; d < 64; ++d) sc += qrow[d] * krow[d];
    float m = sc;
#pragma unroll
    for (int o = 32; o >= 1; o >>= 1) m = fmaxf(m, __shfl_xor(m, o));
    int wid = tid >> 6, lane = tid & 63;
    if (lane == 0) red[wid] = m;
    __syncthreads();
    m = fmaxf(fmaxf(red[0], red[1]), fmaxf(red[2], red[3]));
    float p = __expf(sc - m);
    float s = p;
#pragma unroll
    for (int o = 32; o >= 1; o >>= 1) s += __shfl_xor(s, o);
    if (lane == 0) red2[wid] = s;
    __syncthreads();
    s = red2[0] + red2[1] + red2[2] + red2[3];
    a2[((size_t)hh * 256 + i) * 256 + tid] = p / s;
}

// ---------------- pinv: per-head max row/col sums ----------------
__global__ __launch_bounds__(256) void pinv_norms(const float* __restrict__ x, float* __restrict__ scr)
{
    int hh = blockIdx.x;
    const float* xh = x + ((size_t)hh << 16);
    int tid = threadIdx.x;
    float rs = 0.f, cs = 0.f;
    for (int j = 0; j < 256; ++j) rs += fabsf(xh[tid * 256 + j]);
    for (int i = 0; i < 256; ++i) cs += fabsf(xh[i * 256 + tid]);
#pragma unroll
    for (int o = 32; o >= 1; o >>= 1) { rs = fmaxf(rs, __shfl_xor(rs, o)); cs = fmaxf(cs, __shfl_xor(cs, o)); }
    __shared__ float r4[4], c4[4];
    int wid = tid >> 6, lane = tid & 63;
    if (lane == 0) { r4[wid] = rs; c4[wid] = cs; }
    __syncthreads();
    if (tid == 0) {
        scr[hh]     = fmaxf(fmaxf(r4[0], r4[1]), fmaxf(r4[2], r4[3]));
        scr[8 + hh] = fmaxf(fmaxf(c4[0], c4[1]), fmaxf(c4[2], c4[3]));
    }
}

// z0 = x^T / (col*row), col/row are GLOBAL maxima across heads
__global__ __launch_bounds__(256) void pinv_transpose(
    const float* __restrict__ x, const float* __restrict__ scr, float* __restrict__ z)
{
    float col = scr[0], row = scr[8];
#pragma unroll
    for (int k = 1; k < 8; ++k) { col = fmaxf(col, scr[k]); row = fmaxf(row, scr[8 + k]); }
    float s = 1.f / (col * row);
    int idx = blockIdx.x * 256 + threadIdx.x;
    int hh = idx >> 16, rem = idx & 65535, j = rem >> 8, i = rem & 255;
    z[idx] = x[((size_t)hh << 16) + (i << 8) + j] * s;
}

// ---------------- batched per-head 256x256: C = scl*(alpha*A - A@B) ----------------
__global__ __launch_bounds__(256) void gemm256_pinv(
    const float* __restrict__ A, const float* __restrict__ B, float* __restrict__ C,
    float alpha, float scl)
{
    int hh = blockIdx.x >> 4, t = blockIdx.x & 15;
    int row0 = (t >> 2) * 64, col0 = (t & 3) * 64;
    const float* Ah = A + ((size_t)hh << 16);
    const float* Bh = B + ((size_t)hh << 16);
    float* Ch = C + ((size_t)hh << 16);
    int tid = threadIdx.x;
    int tx = tid & 15, ty = tid >> 4;
    __shared__ __align__(16) float As[16][64];
    __shared__ __align__(16) float Bs[16][64];
    int lr = tid >> 2, lk = (tid & 3) << 2;       // A loader (transposed store)
    int bk = tid >> 4, bc = (tid & 15) << 2;      // B loader (direct store)
    float acc[4][4] = {};
    for (int kt = 0; kt < 256; kt += 16) {
        float4 a = *(const float4*)(Ah + (size_t)(row0 + lr) * 256 + kt + lk);
        float4 b = *(const float4*)(Bh + (size_t)(kt + bk) * 256 + col0 + bc);
        As[lk + 0][lr] = a.x; As[lk + 1][lr] = a.y; As[lk + 2][lr] = a.z; As[lk + 3][lr] = a.w;
        *(float4*)(&Bs[bk][bc]) = b;
        __syncthreads();
#pragma unroll
        for (int k = 0; k < 16; ++k) {
            float4 av = *(const float4*)(&As[k][ty << 2]);
            float4 bv = *(const float4*)(&Bs[k][tx << 2]);
            acc[0][0] += av.x * bv.x; acc[0][1] += av.x * bv.y; acc[0][2] += av.x * bv.z; acc[0][3] += av.x * bv.w;
            acc[1][0] += av.y * bv.x; acc[1][1] += av.y * bv.y; acc[1][2] += av.y * bv.z; acc[1][3] += av.y * bv.w;
            acc[2][0] += av.z * bv.x; acc[2][1] += av.z * bv.y; acc[2][2] += av.z * bv.z; acc[2][3] += av.z * bv.w;
            acc[3][0] += av.w * bv.x; acc[3][1] += av.w * bv.y; acc[3][2] += av.w * bv.z; acc[3][3] += av.w * bv.w;
        }
        __syncthreads();
    }
#pragma unroll
    for (int i = 0; i < 4; ++i) {
        int rr = row0 + (ty << 2) + i, cc = col0 + (tx << 2);
        float4 ae = *(const float4*)(Ah + (size_t)rr * 256 + cc);
        float4 o;
        o.x = scl * (alpha * ae.x - acc[i][0]);
        o.y = scl * (alpha * ae.y - acc[i][1]);
        o.z = scl * (alpha * ae.z - acc[i][2]);
        o.w = scl * (alpha * ae.w - acc[i][3]);
        *(float4*)(Ch + (size_t)rr * 256 + cc) = o;
    }
}

// ---------------- stage A: av = softmax(0.125 * q_l @ k^T) @ v, online over N keys ----------------
__global__ __launch_bounds__(256) void stage_a(
    const float* __restrict__ qkv, const float* __restrict__ ql, float* __restrict__ av, int N)
{
    int hh = blockIdx.y;
    int q0 = blockIdx.x * 8;
    int tid = threadIdx.x;
    int lane = tid & 63, wid = tid >> 6;
    __shared__ float qs[8][64];
    __shared__ float kv[128 * 65];
    __shared__ float ss[8][128];
    __shared__ float ps[8][128];
    __shared__ float mrow[8], srow[8], scalef[8];
    for (int t = tid; t < 512; t += 256) {
        int r = t >> 6, d = t & 63;
        qs[r][d] = 0.125f * ql[(q0 + r) * 512 + hh * 64 + d];
    }
    if (tid < 8) { mrow[tid] = -1e30f; srow[tid] = 0.f; }
    int d = tid & 63, sub = tid >> 6;
    float acc0 = 0.f, acc1 = 0.f;
    __syncthreads();
    for (int kb = 0; kb < N; kb += 128) {
        for (int t = tid; t < 8192; t += 256) {
            int r = t >> 6, dd = t & 63;
            kv[r * 65 + dd] = qkv[(size_t)(kb + r) * QKVLD + 512 + hh * 64 + dd];
        }
        __syncthreads();
        {
            int j = tid & 127;
            int rb = (tid >> 7) * 4;
            float s0 = 0, s1 = 0, s2 = 0, s3 = 0;
#pragma unroll
            for (int dd = 0; dd < 64; ++dd) {
                float kvv = kv[j * 65 + dd];
                s0 += qs[rb + 0][dd] * kvv;
                s1 += qs[rb + 1][dd] * kvv;
                s2 += qs[rb + 2][dd] * kvv;
                s3 += qs[rb + 3][dd] * kvv;
            }
            ss[rb + 0][j] = s0; ss[rb + 1][j] = s1; ss[rb + 2][j] = s2; ss[rb + 3][j] = s3;
        }
        __syncthreads();
#pragma unroll
        for (int rr = 0; rr < 2; ++rr) {
            int row = wid + rr * 4;
            float a = ss[row][lane], b2 = ss[row][lane + 64];
            float mx = fmaxf(a, b2);
#pragma unroll
            for (int o = 32; o >= 1; o >>= 1) mx = fmaxf(mx, __shfl_xor(mx, o));
            float newm = fmaxf(mrow[row], mx);
            float pa = __expf(a - newm), pb = __expf(b2 - newm);
            ps[row][lane] = pa; ps[row][lane + 64] = pb;
            float sum = pa + pb;
#pragma unroll
            for (int o = 32; o >= 1; o >>= 1) sum += __shfl_xor(sum, o);
            if (lane == 0) {
                float f = __expf(mrow[row] - newm);
                scalef[row] = f;
                srow[row] = srow[row] * f + sum;
                mrow[row] = newm;
            }
        }
        __syncthreads();
        acc0 *= scalef[sub];
        acc1 *= scalef[sub + 4];
        for (int t = tid; t < 8192; t += 256) {
            int r = t >> 6, dd = t & 63;
            kv[r * 65 + dd] = qkv[(size_t)(kb + r) * QKVLD + 1024 + hh * 64 + dd];
        }
        __syncthreads();
#pragma unroll 4
        for (int j = 0; j < 128; ++j) {
            float vv = kv[j * 65 + d];
            acc0 += ps[sub][j] * vv;
            acc1 += ps[sub + 4][j] * vv;
        }
        __syncthreads();
    }
    av[((size_t)hh * 256 + q0 + sub) * 64 + d]     = acc0 / srow[sub];
    av[((size_t)hh * 256 + q0 + sub + 4) * 64 + d] = acc1 / srow[sub + 4];
}

// ---------------- t2m = attn2_inv @ av (per head, 256x256 @ 256x64) ----------------
__global__ __launch_bounds__(256) void zmm_kernel(
    const float* __restrict__ Z, const float* __restrict__ av, float* __restrict__ t2m)
{
    int hh = blockIdx.y;
    int row0 = blockIdx.x * 64;
    int tid = threadIdx.x;
    int r = tid >> 2, q = tid & 3;
    __shared__ float zs[64][65];
    __shared__ float vs[64][65];
    float acc[16] = {};
#pragma unroll 4
    for (int kc = 0; kc < 4; ++kc) {
        __syncthreads();
        for (int t = tid; t < 4096; t += 256) {
            int a = t >> 6, dd = t & 63;
            zs[a][dd] = Z[((size_t)hh << 16) + (row0 + a) * 256 + kc * 64 + dd];
            vs[a][dd] = av[((size_t)hh * 256 + kc * 64 + a) * 64 + dd];
        }
        __syncthreads();
#pragma unroll
        for (int k = 0; k < 64; ++k) {
            float z = zs[r][k];
#pragma unroll
            for (int dd = 0; dd < 16; ++dd) acc[dd] += z * vs[k][q * 16 + dd];
        }
    }
    float* op = t2m + ((size_t)hh * 256 + row0 + r) * 64 + q * 16;
    *(float4*)(op + 0)  = make_float4(acc[0], acc[1], acc[2], acc[3]);
    *(float4*)(op + 4)  = make_float4(acc[4], acc[5], acc[6], acc[7]);
    *(float4*)(op + 8)  = make_float4(acc[8], acc[9], acc[10], acc[11]);
    *(float4*)(op + 12) = make_float4(acc[12], acc[13], acc[14], acc[15]);
}

// ---------------- stage C: oh[rows] = softmax(0.125 * q @ k_l^T) @ t2m ----------------
__global__ __launch_bounds__(256) void stage_c(
    const float* __restrict__ qkv, const float* __restrict__ kl,
    const float* __restrict__ t2m, float* __restrict__ oh, int r0)
{
    int hh = blockIdx.y;
    int row0 = r0 + blockIdx.x * 64;
    int tid = threadIdx.x;
    int r = tid >> 2, q = tid & 3;
    __shared__ float qs[64][65];
    __shared__ float cs[64][65];
    __shared__ float pl[64][65];
    for (int t = tid; t < 4096; t += 256) {
        int rr = t >> 6, dd = t & 63;
        qs[rr][dd] = 0.125f * qkv[(size_t)(row0 + rr) * QKVLD + hh * 64 + dd];
    }
    float sc[4][16];
#pragma unroll 4
    for (int c = 0; c < 4; ++c) {
        __syncthreads();
        for (int t = tid; t < 4096; t += 256) {
            int jl = t >> 6, dd = t & 63;
            cs[jl][dd] = kl[(c * 64 + jl) * 512 + hh * 64 + dd];
        }
        __syncthreads();
#pragma unroll
        for (int jj = 0; jj < 16; ++jj) {
            int jl = q * 16 + jj;
            float s = 0.f;
#pragma unroll
            for (int dd = 0; dd < 64; ++dd) s += qs[r][dd] * cs[jl][dd];
            sc[c][jj] = s;
        }
    }
    float m = -1e30f;
#pragma unroll
    for (int c = 0; c < 4; ++c)
#pragma unroll
        for (int jj = 0; jj < 16; ++jj) m = fmaxf(m, sc[c][jj]);
    m = fmaxf(m, __shfl_xor(m, 1));
    m = fmaxf(m, __shfl_xor(m, 2));
    float ssum = 0.f;
#pragma unroll
    for (int c = 0; c < 4; ++c)
#pragma unroll
        for (int jj = 0; jj < 16; ++jj) { sc[c][jj] = __expf(sc[c][jj] - m); ssum += sc[c][jj]; }
    ssum += __shfl_xor(ssum, 1);
    ssum += __shfl_xor(ssum, 2);
    float invs = 1.f / ssum;
    float acc[16] = {};
#pragma unroll 4
    for (int c2 = 0; c2 < 4; ++c2) {
        __syncthreads();
#pragma unroll
        for (int jj = 0; jj < 16; ++jj) pl[r][q * 16 + jj] = sc[c2][jj];
        for (int t = tid; t < 4096; t += 256) {
            int jl = t >> 6, dd = t & 63;
            cs[jl][dd] = t2m[((size_t)hh * 256 + c2 * 64 + jl) * 64 + dd];
        }
        __syncthreads();
#pragma unroll
        for (int j = 0; j < 64; ++j) {
            float p = pl[r][j];
#pragma unroll
            for (int dd = 0; dd < 16; ++dd) acc[dd] += p * cs[j][q * 16 + dd];
        }
    }
    float* op = oh + (size_t)(row0 + r) * 512 + hh * 64 + q * 16;
    *(float4*)(op + 0)  = make_float4(acc[0] * invs, acc[1] * invs, acc[2] * invs, acc[3] * invs);
    *(float4*)(op + 4)  = make_float4(acc[4] * invs, acc[5] * invs, acc[6] * invs, acc[7] * invs);
    *(float4*)(op + 8)  = make_float4(acc[8] * invs, acc[9] * invs, acc[10] * invs, acc[11] * invs);
    *(float4*)(op + 12) = make_float4(acc[12] * invs, acc[13] * invs, acc[14] * invs, acc[15] * invs);
}

// ---------------- depthwise conv (k=33): 8 output rows per thread, sliding window ----------------
__global__ __launch_bounds__(256) void conv_kernel(
    const float* __restrict__ qkv, const float* __restrict__ w,
    float* __restrict__ oh, int r0, int nrows, int N)
{
    int idx = blockIdx.x * 256 + threadIdx.x;
    int nrb = (nrows + 7) >> 3;
    if (idx >= nrb * 512) return;
    int rb = idx >> 9, c = idx & 511;
    int hh = c >> 6;
    int g0 = r0 + rb * 8;
    float wr[33];
#pragma unroll
    for (int k = 0; k < 33; ++k) wr[k] = w[hh * 33 + k];
    float acc[8] = {};
#pragma unroll
    for (int t = 0; t < 41; ++t) {
        int row = g0 + t - 16;
        float v = (row >= 0 && row < N) ? qkv[(size_t)row * QKVLD + 1024 + c] : 0.f;
#pragma unroll
        for (int i = 0; i < 8; ++i) {
            int k = t - i;
            if (k >= 0 && k < 33) acc[i] += wr[k] * v;
        }
    }
#pragma unroll
    for (int i = 0; i < 8; ++i) {
        int g = g0 + i;
        if (g < r0 + nrows) oh[(size_t)g * 512 + c] += acc[i];
    }
}

// ---------------- layer2 final projection: 4 rows only ----------------
__global__ __launch_bounds__(256) void l2out_kernel(
    const float* __restrict__ oh, const float* __restrict__ W,
    const float* __restrict__ bias, const float* __restrict__ bott,
    const float* __restrict__ omega, float* __restrict__ bn_new)
{
    int idx = blockIdx.x * 256 + threadIdx.x;  // 4*512
    int i = idx >> 9, j = idx & 511;
    float acc = bias[j];
    const float* ar = oh + (size_t)(252 + i) * 512;
    const float* wr = W + (size_t)j * 512;
    for (int k = 0; k < 512; ++k) acc += ar[k] * wr[k];
    bn_new[idx] = bott[idx] * omega[0] + acc;
}

// ---------------- host ----------------
static void run_layer_common(const float* src1, int n1, const float* src2,
                             const float* lnw, const float* lnb, const float* qkvw,
                             int N, int l,
                             float* h, float* qkv, float* ql, float* kl,
                             float* a2, float* z0, float* z1, float* xz,
                             float* ta, float* tb, float* avb, float* t2m,
                             float* scr, float** z_final, hipStream_t stream)
{
    ln_pad_kernel<<<N, 256, 0, stream>>>(src1, n1, src2, lnw, lnb, h, 252);
    dim3 g1(N / 128, 12);
    gemm_nt128<<<g1, 256, 0, stream>>>(h, qkvw, qkv, 512, 512, 512, QKVLD, nullptr, nullptr, nullptr);
    landmarks_kernel<<<256, 256, 0, stream>>>(qkv, ql, kl, l);
    attn2_kernel<<<dim3(256, 8), 256, 0, stream>>>(ql, kl, a2);
    pinv_norms<<<8, 256, 0, stream>>>(a2, scr);
    pinv_transpose<<<2048, 256, 0, stream>>>(a2, scr, z0);
    float* zc = z0; float* zn = z1;
    for (int it = 0; it < 6; ++it) {
        gemm256_pinv<<<128, 256, 0, stream>>>(a2, zc, xz, 0.f, -1.f);   // xz = a2@z
        gemm256_pinv<<<128, 256, 0, stream>>>(xz, xz, ta, 7.f, 1.f);    // ta = 7xz - xz@xz
        gemm256_pinv<<<128, 256, 0, stream>>>(xz, ta, tb, 15.f, 1.f);   // tb = 15xz - xz@ta
        gemm256_pinv<<<128, 256, 0, stream>>>(zc, tb, zn, 13.f, 0.25f); // z  = .25(13z - z@tb)
        float* tmp = zc; zc = zn; zn = tmp;
    }
    stage_a<<<dim3(32, 8), 256, 0, stream>>>(qkv, ql, avb, N);
    zmm_kernel<<<dim3(4, 8), 256, 0, stream>>>(zc, avb, t2m);
    *z_final = zc;
}

extern "C" void kernel_launch(void* const* d_in, const int* in_sizes, int n_in,
                              void* d_out, int out_size, void* d_ws, size_t ws_size,
                              hipStream_t stream) {
    (void)in_sizes; (void)n_in; (void)out_size; (void)ws_size;
    const float* x1    = (const float*)d_in[0];
    const float* x2    = (const float*)d_in[1];
    const float* bott  = (const float*)d_in[2];
    const float* ln1w  = (const float*)d_in[3];
    const float* ln1b  = (const float*)d_in[4];
    const float* qkv1w = (const float*)d_in[5];
    const float* out1w = (const float*)d_in[6];
    const float* out1b = (const float*)d_in[7];
    const float* cv1w  = (const float*)d_in[8];
    const float* om1   = (const float*)d_in[9];
    const float* ln2w  = (const float*)d_in[10];
    const float* ln2b  = (const float*)d_in[11];
    const float* qkv2w = (const float*)d_in[12];
    const float* out2w = (const float*)d_in[13];
    const float* out2b = (const float*)d_in[14];
    const float* cv2w  = (const float*)d_in[15];
    const float* om2   = (const float*)d_in[16];

    const int N1 = 16640, N2 = 2304;
    float* ws = (float*)d_ws;
    size_t off = 0;
    float* h    = ws + off; off += (size_t)N1 * 512;   // aliased: LN output, then attention output (oh)
    float* oh   = h;                                   // h is dead after the QKV GEMM
    float* qkv  = ws + off; off += (size_t)N1 * 1536;
    float* ql   = ws + off; off += 256 * 512;
    float* kl   = ws + off; off += 256 * 512;
    float* a2   = ws + off; off += (size_t)8 * 65536;
    float* z0   = ws + off; off += (size_t)8 * 65536;
    float* z1   = ws + off; off += (size_t)8 * 65536;
    float* xz   = ws + off; off += (size_t)8 * 65536;
    float* ta   = ws + off; off += (size_t)8 * 65536;
    float* tb   = ws + off; off += (size_t)8 * 65536;
    float* avb  = ws + off; off += (size_t)8 * 256 * 64;
    float* t2m  = ws + off; off += (size_t)8 * 256 * 64;
    float* bnn  = ws + off; off += 4 * 512;
    float* scr  = ws + off; off += 64;

    float* zf = nullptr;

    // ---- layer 2 (bottleneck path): only first 4 output rows are consumed ----
    run_layer_common(bott, 4, x2, ln2w, ln2b, qkv2w, N2, 9,
                     h, qkv, ql, kl, a2, z0, z1, xz, ta, tb, avb, t2m, scr, &zf, stream);
    stage_c<<<dim3(1, 8), 256, 0, stream>>>(qkv, kl, t2m, oh, 252);
    {
        int nrb = 1, thr = nrb * 512;
        conv_kernel<<<(thr + 255) / 256, 256, 0, stream>>>(qkv, cv2w, oh, 252, 4, N2);
    }
    l2out_kernel<<<8, 256, 0, stream>>>(oh, out2w, out2b, bott, om2, bnn);

    // ---- layer 1 (main path) ----
    run_layer_common(x1, 16384, bnn, ln1w, ln1b, qkv1w, N1, 65,
                     h, qkv, ql, kl, a2, z0, z1, xz, ta, tb, avb, t2m, scr, &zf, stream);
    stage_c<<<dim3(256, 8), 256, 0, stream>>>(qkv, kl, t2m, oh, 252);
    {
        int nrb = 16384 / 8, thr = nrb * 512;
        conv_kernel<<<(thr + 255) / 256, 256, 0, stream>>>(qkv, cv1w, oh, 252, 16384, N1);
    }
    dim3 g2(16384 / 128, 4);
    gemm_nt128<<<g2, 256, 0, stream>>>(oh + (size_t)252 * 512, out1w, (float*)d_out,
                                       512, 512, 512, 512, x1, out1b, om1);
}

// Round 4
// 4136.024 us; speedup vs baseline: 3.4266x; 3.4266x over previous
//
#include <hip/hip_runtime.h>
#include <math.h>

#define QKVLD 1536

// ---------------- LayerNorm with front zero-padding ----------------
__global__ __launch_bounds__(256) void ln_pad_kernel(
    const float* __restrict__ src1, int n1,
    const float* __restrict__ src2,
    const float* __restrict__ w, const float* __restrict__ b,
    float* __restrict__ h, int pad)
{
    int r = blockIdx.x;
    int tid = threadIdx.x;
    float* out = h + (size_t)r * 512;
    if (r < pad) { out[tid] = 0.f; out[tid + 256] = 0.f; return; }
    int i = r - pad;
    const float* src = (i < n1) ? (src1 + (size_t)i * 512)
                                : (src2 + (size_t)(i - n1) * 512);
    float x0 = src[tid], x1 = src[tid + 256];
    float s = x0 + x1, sq = x0 * x0 + x1 * x1;
#pragma unroll
    for (int o = 32; o >= 1; o >>= 1) { s += __shfl_xor(s, o); sq += __shfl_xor(sq, o); }
    __shared__ float rs[4], rq[4];
    int wid = tid >> 6, lane = tid & 63;
    if (lane == 0) { rs[wid] = s; rq[wid] = sq; }
    __syncthreads();
    s = rs[0] + rs[1] + rs[2] + rs[3];
    sq = rq[0] + rq[1] + rq[2] + rq[3];
    float mu = s * (1.f / 512.f);
    float var = sq * (1.f / 512.f) - mu * mu;
    float inv = rsqrtf(var + 1e-5f);
    out[tid]       = (x0 - mu) * inv * w[tid] + b[tid];
    out[tid + 256] = (x1 - mu) * inv * w[tid + 256] + b[tid + 256];
}

// ---------------- GEMM C[M x Nc] = A[M x K] @ B[Nc x K]^T, 128x128 tile, 8x8/thread ----
__global__ __launch_bounds__(256) void gemm_nt128(
    const float* __restrict__ A, const float* __restrict__ B, float* __restrict__ C,
    int K, int lda, int ldb, int ldc,
    const float* __restrict__ resid, const float* __restrict__ bias,
    const float* __restrict__ omega)
{
    __shared__ __align__(16) float As[16][128];
    __shared__ __align__(16) float Bs[16][128];
    int tid = threadIdx.x;
    int tx = tid & 15, ty = tid >> 4;
    int row0 = blockIdx.x * 128, col0 = blockIdx.y * 128;
    int lr = tid >> 1, lk = (tid & 1) << 3;   // each thread: 1 row, 8 consecutive k
    const float* Ap = A + (size_t)(row0 + lr) * lda + lk;
    const float* Bp = B + (size_t)(col0 + lr) * ldb + lk;
    float acc[8][8] = {};
    float4 a0 = *(const float4*)(Ap);
    float4 a1 = *(const float4*)(Ap + 4);
    float4 b0 = *(const float4*)(Bp);
    float4 b1 = *(const float4*)(Bp + 4);
    for (int kt = 0; kt < K; kt += 16) {
        __syncthreads();
        As[lk + 0][lr] = a0.x; As[lk + 1][lr] = a0.y; As[lk + 2][lr] = a0.z; As[lk + 3][lr] = a0.w;
        As[lk + 4][lr] = a1.x; As[lk + 5][lr] = a1.y; As[lk + 6][lr] = a1.z; As[lk + 7][lr] = a1.w;
        Bs[lk + 0][lr] = b0.x; Bs[lk + 1][lr] = b0.y; Bs[lk + 2][lr] = b0.z; Bs[lk + 3][lr] = b0.w;
        Bs[lk + 4][lr] = b1.x; Bs[lk + 5][lr] = b1.y; Bs[lk + 6][lr] = b1.z; Bs[lk + 7][lr] = b1.w;
        __syncthreads();
        if (kt + 16 < K) {
            a0 = *(const float4*)(Ap + kt + 16); a1 = *(const float4*)(Ap + kt + 20);
            b0 = *(const float4*)(Bp + kt + 16); b1 = *(const float4*)(Bp + kt + 20);
        }
#pragma unroll
        for (int k = 0; k < 16; ++k) {
            float4 av0 = *(const float4*)(&As[k][ty << 2]);
            float4 av1 = *(const float4*)(&As[k][64 + (ty << 2)]);
            float4 bv0 = *(const float4*)(&Bs[k][tx << 2]);
            float4 bv1 = *(const float4*)(&Bs[k][64 + (tx << 2)]);
            float a[8] = {av0.x, av0.y, av0.z, av0.w, av1.x, av1.y, av1.z, av1.w};
            float bb[8] = {bv0.x, bv0.y, bv0.z, bv0.w, bv1.x, bv1.y, bv1.z, bv1.w};
#pragma unroll
            for (int i = 0; i < 8; ++i)
#pragma unroll
                for (int j = 0; j < 8; ++j) acc[i][j] += a[i] * bb[j];
        }
    }
#pragma unroll
    for (int ih = 0; ih < 2; ++ih)
#pragma unroll
    for (int i = 0; i < 4; ++i) {
        int r = row0 + ih * 64 + (ty << 2) + i;
#pragma unroll
        for (int jh = 0; jh < 2; ++jh) {
            int c = col0 + jh * 64 + (tx << 2);
            float4 o = make_float4(acc[ih * 4 + i][jh * 4 + 0], acc[ih * 4 + i][jh * 4 + 1],
                                   acc[ih * 4 + i][jh * 4 + 2], acc[ih * 4 + i][jh * 4 + 3]);
            if (resid) {
                float om = omega[0];
                float4 rv = *(const float4*)(resid + (size_t)r * ldc + c);
                float4 bv = *(const float4*)(bias + c);
                o.x += om * rv.x + bv.x; o.y += om * rv.y + bv.y;
                o.z += om * rv.z + bv.z; o.w += om * rv.w + bv.w;
            }
            *(float4*)(C + (size_t)r * ldc + c) = o;
        }
    }
}

// ---------------- landmark means (q_l, k_l) ----------------
__global__ __launch_bounds__(256) void landmarks_kernel(
    const float* __restrict__ qkv, float* __restrict__ ql, float* __restrict__ kl, int l)
{
    int j = blockIdx.x;
    int tid = threadIdx.x;
    float inv = 1.f / (float)l;
    const float* base = qkv + (size_t)j * l * QKVLD;
    float sq0 = 0, sq1 = 0, sk0 = 0, sk1 = 0;
    for (int r = 0; r < l; ++r) {
        const float* row = base + (size_t)r * QKVLD;
        sq0 += row[tid]; sq1 += row[tid + 256];
        sk0 += row[512 + tid]; sk1 += row[512 + tid + 256];
    }
    ql[j * 512 + tid] = sq0 * inv; ql[j * 512 + tid + 256] = sq1 * inv;
    kl[j * 512 + tid] = sk0 * inv; kl[j * 512 + tid + 256] = sk1 * inv;
}

// ---------------- attn2 = softmax(0.125 * q_l @ k_l^T) per head ----------------
__global__ __launch_bounds__(256) void attn2_kernel(
    const float* __restrict__ ql, const float* __restrict__ kl, float* __restrict__ a2)
{
    int hh = blockIdx.y, i = blockIdx.x;
    int tid = threadIdx.x;
    __shared__ float qrow[64];
    __shared__ float red[4], red2[4];
    if (tid < 64) qrow[tid] = 0.125f * ql[i * 512 + hh * 64 + tid];
    __syncthreads();
    const float* krow = kl + (size_t)tid * 512 + hh * 64;
    float sc = 0.f;
#pragma unroll
    for (int d = 0; d < 64; ++d) sc += qrow[d] * krow[d];
    float m = sc;
#pragma unroll
    for (int o = 32; o >= 1; o >>= 1) m = fmaxf(m, __shfl_xor(m, o));
    int wid = tid >> 6, lane = tid & 63;
    if (lane == 0) red[wid] = m;
    __syncthreads();
    m = fmaxf(fmaxf(red[0], red[1]), fmaxf(red[2], red[3]));
    float p = __expf(sc - m);
    float s = p;
#pragma unroll
    for (int o = 32; o >= 1; o >>= 1) s += __shfl_xor(s, o);
    if (lane == 0) red2[wid] = s;
    __syncthreads();
    s = red2[0] + red2[1] + red2[2] + red2[3];
    a2[((size_t)hh * 256 + i) * 256 + tid] = p / s;
}

// ---------------- pinv: per-head max row/col sums ----------------
__global__ __launch_bounds__(256) void pinv_norms(const float* __restrict__ x, float* __restrict__ scr)
{
    int hh = blockIdx.x;
    const float* xh = x + ((size_t)hh << 16);
    int tid = threadIdx.x;
    float rs = 0.f, cs = 0.f;
    for (int j = 0; j < 256; ++j) rs += fabsf(xh[tid * 256 + j]);
    for (int i = 0; i < 256; ++i) cs += fabsf(xh[i * 256 + tid]);
#pragma unroll
    for (int o = 32; o >= 1; o >>= 1) { rs = fmaxf(rs, __shfl_xor(rs, o)); cs = fmaxf(cs, __shfl_xor(cs, o)); }
    __shared__ float r4[4], c4[4];
    int wid = tid >> 6, lane = tid & 63;
    if (lane == 0) { r4[wid] = rs; c4[wid] = cs; }
    __syncthreads();
    if (tid == 0) {
        scr[hh]     = fmaxf(fmaxf(r4[0], r4[1]), fmaxf(r4[2], r4[3]));
        scr[8 + hh] = fmaxf(fmaxf(c4[0], c4[1]), fmaxf(c4[2], c4[3]));
    }
}

// z0 = x^T / (col*row), col/row are GLOBAL maxima across heads
__global__ __launch_bounds__(256) void pinv_transpose(
    const float* __restrict__ x, const float* __restrict__ scr, float* __restrict__ z)
{
    float col = scr[0], row = scr[8];
#pragma unroll
    for (int k = 1; k < 8; ++k) { col = fmaxf(col, scr[k]); row = fmaxf(row, scr[8 + k]); }
    float s = 1.f / (col * row);
    int idx = blockIdx.x * 256 + threadIdx.x;
    int hh = idx >> 16, rem = idx & 65535, j = rem >> 8, i = rem & 255;
    z[idx] = x[((size_t)hh << 16) + (i << 8) + j] * s;
}

// ---------------- batched per-head 256x256: C = scl*(alpha*A - A@B) ----------------
__global__ __launch_bounds__(256) void gemm256_pinv(
    const float* __restrict__ A, const float* __restrict__ B, float* __restrict__ C,
    float alpha, float scl)
{
    int hh = blockIdx.x >> 4, t = blockIdx.x & 15;
    int row0 = (t >> 2) * 64, col0 = (t & 3) * 64;
    const float* Ah = A + ((size_t)hh << 16);
    const float* Bh = B + ((size_t)hh << 16);
    float* Ch = C + ((size_t)hh << 16);
    int tid = threadIdx.x;
    int tx = tid & 15, ty = tid >> 4;
    __shared__ __align__(16) float As[16][64];
    __shared__ __align__(16) float Bs[16][64];
    int lr = tid >> 2, lk = (tid & 3) << 2;       // A loader (transposed store)
    int bk = tid >> 4, bc = (tid & 15) << 2;      // B loader (direct store)
    float acc[4][4] = {};
    float4 a = *(const float4*)(Ah + (size_t)(row0 + lr) * 256 + lk);
    float4 b = *(const float4*)(Bh + (size_t)bk * 256 + col0 + bc);
    for (int kt = 0; kt < 256; kt += 16) {
        __syncthreads();
        As[lk + 0][lr] = a.x; As[lk + 1][lr] = a.y; As[lk + 2][lr] = a.z; As[lk + 3][lr] = a.w;
        *(float4*)(&Bs[bk][bc]) = b;
        __syncthreads();
        if (kt + 16 < 256) {
            a = *(const float4*)(Ah + (size_t)(row0 + lr) * 256 + kt + 16 + lk);
            b = *(const float4*)(Bh + (size_t)(kt + 16 + bk) * 256 + col0 + bc);
        }
#pragma unroll
        for (int k = 0; k < 16; ++k) {
            float4 av = *(const float4*)(&As[k][ty << 2]);
            float4 bv = *(const float4*)(&Bs[k][tx << 2]);
            acc[0][0] += av.x * bv.x; acc[0][1] += av.x * bv.y; acc[0][2] += av.x * bv.z; acc[0][3] += av.x * bv.w;
            acc[1][0] += av.y * bv.x; acc[1][1] += av.y * bv.y; acc[1][2] += av.y * bv.z; acc[1][3] += av.y * bv.w;
            acc[2][0] += av.z * bv.x; acc[2][1] += av.z * bv.y; acc[2][2] += av.z * bv.z; acc[2][3] += av.z * bv.w;
            acc[3][0] += av.w * bv.x; acc[3][1] += av.w * bv.y; acc[3][2] += av.w * bv.z; acc[3][3] += av.w * bv.w;
        }
    }
#pragma unroll
    for (int i = 0; i < 4; ++i) {
        int rr = row0 + (ty << 2) + i, cc = col0 + (tx << 2);
        float4 ae = *(const float4*)(Ah + (size_t)rr * 256 + cc);
        float4 o;
        o.x = scl * (alpha * ae.x - acc[i][0]);
        o.y = scl * (alpha * ae.y - acc[i][1]);
        o.z = scl * (alpha * ae.z - acc[i][2]);
        o.w = scl * (alpha * ae.w - acc[i][3]);
        *(float4*)(Ch + (size_t)rr * 256 + cc) = o;
    }
}

// ---------------- stage A: av = softmax(0.125 * q_l @ k^T) @ v, online over N keys ----------------
// float4 global staging (coalesced dwordx4), scalar LDS stores keep the %65 conflict-free pad
__global__ __launch_bounds__(256) void stage_a(
    const float* __restrict__ qkv, const float* __restrict__ ql, float* __restrict__ av, int N)
{
    int hh = blockIdx.y;
    int q0 = blockIdx.x * 8;
    int tid = threadIdx.x;
    int lane = tid & 63, wid = tid >> 6;
    __shared__ float qs[8][64];
    __shared__ float kv[128 * 65];
    __shared__ float ss[8][128];
    __shared__ float ps[8][128];
    __shared__ float mrow[8], srow[8], scalef[8];
    for (int t = tid; t < 512; t += 256) {
        int r = t >> 6, d = t & 63;
        qs[r][d] = 0.125f * ql[(q0 + r) * 512 + hh * 64 + d];
    }
    if (tid < 8) { mrow[tid] = -1e30f; srow[tid] = 0.f; }
    int d = tid & 63, sub = tid >> 6;
    float acc0 = 0.f, acc1 = 0.f;
    __syncthreads();
    for (int kb = 0; kb < N; kb += 128) {
#pragma unroll
        for (int t = tid; t < 2048; t += 256) {
            int r = t >> 4, d4 = (t & 15) << 2;
            float4 vv = *(const float4*)(&qkv[(size_t)(kb + r) * QKVLD + 512 + hh * 64 + d4]);
            kv[r * 65 + d4 + 0] = vv.x; kv[r * 65 + d4 + 1] = vv.y;
            kv[r * 65 + d4 + 2] = vv.z; kv[r * 65 + d4 + 3] = vv.w;
        }
        __syncthreads();
        {
            int j = tid & 127;
            int rb = (tid >> 7) * 4;
            float s0 = 0, s1 = 0, s2 = 0, s3 = 0;
#pragma unroll
            for (int dd = 0; dd < 64; ++dd) {
                float kvv = kv[j * 65 + dd];
                s0 += qs[rb + 0][dd] * kvv;
                s1 += qs[rb + 1][dd] * kvv;
                s2 += qs[rb + 2][dd] * kvv;
                s3 += qs[rb + 3][dd] * kvv;
            }
            ss[rb + 0][j] = s0; ss[rb + 1][j] = s1; ss[rb + 2][j] = s2; ss[rb + 3][j] = s3;
        }
        __syncthreads();
#pragma unroll
        for (int rr = 0; rr < 2; ++rr) {
            int row = wid + rr * 4;
            float a = ss[row][lane], b2 = ss[row][lane + 64];
            float mx = fmaxf(a, b2);
#pragma unroll
            for (int o = 32; o >= 1; o >>= 1) mx = fmaxf(mx, __shfl_xor(mx, o));
            float newm = fmaxf(mrow[row], mx);
            float pa = __expf(a - newm), pb = __expf(b2 - newm);
            ps[row][lane] = pa; ps[row][lane + 64] = pb;
            float sum = pa + pb;
#pragma unroll
            for (int o = 32; o >= 1; o >>= 1) sum += __shfl_xor(sum, o);
            if (lane == 0) {
                float f = __expf(mrow[row] - newm);
                scalef[row] = f;
                srow[row] = srow[row] * f + sum;
                mrow[row] = newm;
            }
        }
        __syncthreads();
        acc0 *= scalef[sub];
        acc1 *= scalef[sub + 4];
#pragma unroll
        for (int t = tid; t < 2048; t += 256) {
            int r = t >> 4, d4 = (t & 15) << 2;
            float4 vv = *(const float4*)(&qkv[(size_t)(kb + r) * QKVLD + 1024 + hh * 64 + d4]);
            kv[r * 65 + d4 + 0] = vv.x; kv[r * 65 + d4 + 1] = vv.y;
            kv[r * 65 + d4 + 2] = vv.z; kv[r * 65 + d4 + 3] = vv.w;
        }
        __syncthreads();
#pragma unroll 4
        for (int j = 0; j < 128; ++j) {
            float vv = kv[j * 65 + d];
            acc0 += ps[sub][j] * vv;
            acc1 += ps[sub + 4][j] * vv;
        }
        __syncthreads();
    }
    av[((size_t)hh * 256 + q0 + sub) * 64 + d]     = acc0 / srow[sub];
    av[((size_t)hh * 256 + q0 + sub + 4) * 64 + d] = acc1 / srow[sub + 4];
}

// ---------------- t2m = attn2_inv @ av (per head, 256x256 @ 256x64) ----------------
__global__ __launch_bounds__(256) void zmm_kernel(
    const float* __restrict__ Z, const float* __restrict__ av, float* __restrict__ t2m)
{
    int hh = blockIdx.y;
    int row0 = blockIdx.x * 64;
    int tid = threadIdx.x;
    int r = tid >> 2, q = tid & 3;
    __shared__ float zs[64][65];
    __shared__ float vs[64][65];
    float acc[16] = {};
#pragma unroll 4
    for (int kc = 0; kc < 4; ++kc) {
        __syncthreads();
        for (int t = tid; t < 4096; t += 256) {
            int a = t >> 6, dd = t & 63;
            zs[a][dd] = Z[((size_t)hh << 16) + (row0 + a) * 256 + kc * 64 + dd];
            vs[a][dd] = av[((size_t)hh * 256 + kc * 64 + a) * 64 + dd];
        }
        __syncthreads();
#pragma unroll
        for (int k = 0; k < 64; ++k) {
            float z = zs[r][k];
#pragma unroll
            for (int dd = 0; dd < 16; ++dd) acc[dd] += z * vs[k][q * 16 + dd];
        }
    }
    float* op = t2m + ((size_t)hh * 256 + row0 + r) * 64 + q * 16;
    *(float4*)(op + 0)  = make_float4(acc[0], acc[1], acc[2], acc[3]);
    *(float4*)(op + 4)  = make_float4(acc[4], acc[5], acc[6], acc[7]);
    *(float4*)(op + 8)  = make_float4(acc[8], acc[9], acc[10], acc[11]);
    *(float4*)(op + 12) = make_float4(acc[12], acc[13], acc[14], acc[15]);
}

// ---------------- stage C (flash-style, spill-free): oh = softmax(0.125 q @ kl^T) @ t2m ----
// 64 rows x 1 head per block; online softmax over 4 chunks of 64 landmarks.
__global__ __launch_bounds__(256) void stage_c(
    const float* __restrict__ qkv, const float* __restrict__ kl,
    const float* __restrict__ t2m, float* __restrict__ oh, int r0)
{
    int hh = blockIdx.y;
    int row0 = r0 + blockIdx.x * 64;
    int tid = threadIdx.x;
    int r = tid >> 2, q = tid & 3;          // 4 threads per row (same wave: shfl_xor 1,2)
    __shared__ float qs[64][65];
    __shared__ float cs[64][65];            // time-shared: kl chunk, then t2m chunk
    __shared__ float pl[64][65];
    for (int t = tid; t < 4096; t += 256) {
        int rr = t >> 6, dd = t & 63;
        qs[rr][dd] = 0.125f * qkv[(size_t)(row0 + rr) * QKVLD + hh * 64 + dd];
    }
    float m = -1e30f, l = 0.f;
    float acc[16] = {};
    for (int c = 0; c < 4; ++c) {
        __syncthreads();                    // prev PV reads of cs done
        for (int t = tid; t < 4096; t += 256) {
            int jl = t >> 6, dd = t & 63;
            cs[jl][dd] = kl[(c * 64 + jl) * 512 + hh * 64 + dd];
        }
        __syncthreads();
        float s[16];
        float mx = -1e30f;
#pragma unroll
        for (int jj = 0; jj < 16; ++jj) {
            int jl = q * 16 + jj;
            float sv = 0.f;
#pragma unroll
            for (int dd = 0; dd < 64; ++dd) sv += qs[r][dd] * cs[jl][dd];
            s[jj] = sv;
            mx = fmaxf(mx, sv);
        }
        mx = fmaxf(mx, __shfl_xor(mx, 1));
        mx = fmaxf(mx, __shfl_xor(mx, 2));
        float mn = fmaxf(m, mx);
        float scale = __expf(m - mn);
        m = mn;
        float psum = 0.f;
#pragma unroll
        for (int jj = 0; jj < 16; ++jj) { s[jj] = __expf(s[jj] - mn); psum += s[jj]; }
        psum += __shfl_xor(psum, 1);
        psum += __shfl_xor(psum, 2);
        l = l * scale + psum;
#pragma unroll
        for (int i = 0; i < 16; ++i) acc[i] *= scale;
#pragma unroll
        for (int jj = 0; jj < 16; ++jj) pl[r][q * 16 + jj] = s[jj];
        __syncthreads();                    // pl ready; cs reads (scores) done
        for (int t = tid; t < 4096; t += 256) {
            int jl = t >> 6, dd = t & 63;
            cs[jl][dd] = t2m[((size_t)hh * 256 + c * 64 + jl) * 64 + dd];
        }
        __syncthreads();
#pragma unroll
        for (int j = 0; j < 64; ++j) {
            float p = pl[r][j];
#pragma unroll
            for (int i = 0; i < 16; ++i) acc[i] += p * cs[j][q * 16 + i];
        }
    }
    float invl = 1.f / l;
    float* op = oh + (size_t)(row0 + r) * 512 + hh * 64 + q * 16;
#pragma unroll
    for (int v4 = 0; v4 < 4; ++v4)
        *(float4*)(op + v4 * 4) = make_float4(acc[v4 * 4 + 0] * invl, acc[v4 * 4 + 1] * invl,
                                              acc[v4 * 4 + 2] * invl, acc[v4 * 4 + 3] * invl);
}

// ---------------- depthwise conv (k=33): 8 output rows per thread, sliding window ----------------
__global__ __launch_bounds__(256) void conv_kernel(
    const float* __restrict__ qkv, const float* __restrict__ w,
    float* __restrict__ oh, int r0, int nrows, int N)
{
    int idx = blockIdx.x * 256 + threadIdx.x;
    int nrb = (nrows + 7) >> 3;
    if (idx >= nrb * 512) return;
    int rb = idx >> 9, c = idx & 511;
    int hh = c >> 6;
    int g0 = r0 + rb * 8;
    float wr[33];
#pragma unroll
    for (int k = 0; k < 33; ++k) wr[k] = w[hh * 33 + k];
    float acc[8] = {};
#pragma unroll
    for (int t = 0; t < 41; ++t) {
        int row = g0 + t - 16;
        float v = (row >= 0 && row < N) ? qkv[(size_t)row * QKVLD + 1024 + c] : 0.f;
#pragma unroll
        for (int i = 0; i < 8; ++i) {
            int k = t - i;
            if (k >= 0 && k < 33) acc[i] += wr[k] * v;
        }
    }
#pragma unroll
    for (int i = 0; i < 8; ++i) {
        int g = g0 + i;
        if (g < r0 + nrows) oh[(size_t)g * 512 + c] += acc[i];
    }
}

// ---------------- layer2 final projection: 4 rows only ----------------
__global__ __launch_bounds__(256) void l2out_kernel(
    const float* __restrict__ oh, const float* __restrict__ W,
    const float* __restrict__ bias, const float* __restrict__ bott,
    const float* __restrict__ omega, float* __restrict__ bn_new)
{
    int idx = blockIdx.x * 256 + threadIdx.x;  // 4*512
    int i = idx >> 9, j = idx & 511;
    float acc = bias[j];
    const float* ar = oh + (size_t)(252 + i) * 512;
    const float* wr = W + (size_t)j * 512;
    for (int k = 0; k < 512; ++k) acc += ar[k] * wr[k];
    bn_new[idx] = bott[idx] * omega[0] + acc;
}

// ---------------- host ----------------
static void run_layer_common(const float* src1, int n1, const float* src2,
                             const float* lnw, const float* lnb, const float* qkvw,
                             int N, int l,
                             float* h, float* qkv, float* ql, float* kl,
                             float* a2, float* z0, float* z1, float* xz,
                             float* ta, float* tb, float* avb, float* t2m,
                             float* scr, float** z_final, hipStream_t stream)
{
    ln_pad_kernel<<<N, 256, 0, stream>>>(src1, n1, src2, lnw, lnb, h, 252);
    dim3 g1(N / 128, 12);
    gemm_nt128<<<g1, 256, 0, stream>>>(h, qkvw, qkv, 512, 512, 512, QKVLD, nullptr, nullptr, nullptr);
    landmarks_kernel<<<256, 256, 0, stream>>>(qkv, ql, kl, l);
    attn2_kernel<<<dim3(256, 8), 256, 0, stream>>>(ql, kl, a2);
    pinv_norms<<<8, 256, 0, stream>>>(a2, scr);
    pinv_transpose<<<2048, 256, 0, stream>>>(a2, scr, z0);
    float* zc = z0; float* zn = z1;
    for (int it = 0; it < 6; ++it) {
        gemm256_pinv<<<128, 256, 0, stream>>>(a2, zc, xz, 0.f, -1.f);   // xz = a2@z
        gemm256_pinv<<<128, 256, 0, stream>>>(xz, xz, ta, 7.f, 1.f);    // ta = 7xz - xz@xz
        gemm256_pinv<<<128, 256, 0, stream>>>(xz, ta, tb, 15.f, 1.f);   // tb = 15xz - xz@ta
        gemm256_pinv<<<128, 256, 0, stream>>>(zc, tb, zn, 13.f, 0.25f); // z  = .25(13z - z@tb)
        float* tmp = zc; zc = zn; zn = tmp;
    }
    stage_a<<<dim3(32, 8), 256, 0, stream>>>(qkv, ql, avb, N);
    zmm_kernel<<<dim3(4, 8), 256, 0, stream>>>(zc, avb, t2m);
    *z_final = zc;
}

extern "C" void kernel_launch(void* const* d_in, const int* in_sizes, int n_in,
                              void* d_out, int out_size, void* d_ws, size_t ws_size,
                              hipStream_t stream) {
    (void)in_sizes; (void)n_in; (void)out_size; (void)ws_size;
    const float* x1    = (const float*)d_in[0];
    const float* x2    = (const float*)d_in[1];
    const float* bott  = (const float*)d_in[2];
    const float* ln1w  = (const float*)d_in[3];
    const float* ln1b  = (const float*)d_in[4];
    const float* qkv1w = (const float*)d_in[5];
    const float* out1w = (const float*)d_in[6];
    const float* out1b = (const float*)d_in[7];
    const float* cv1w  = (const float*)d_in[8];
    const float* om1   = (const float*)d_in[9];
    const float* ln2w  = (const float*)d_in[10];
    const float* ln2b  = (const float*)d_in[11];
    const float* qkv2w = (const float*)d_in[12];
    const float* out2w = (const float*)d_in[13];
    const float* out2b = (const float*)d_in[14];
    const float* cv2w  = (const float*)d_in[15];
    const float* om2   = (const float*)d_in[16];

    const int N1 = 16640, N2 = 2304;
    float* ws = (float*)d_ws;
    size_t off = 0;
    float* h    = ws + off; off += (size_t)N1 * 512;   // aliased: LN output, then attention output (oh)
    float* oh   = h;                                   // h is dead after the QKV GEMM
    float* qkv  = ws + off; off += (size_t)N1 * 1536;
    float* ql   = ws + off; off += 256 * 512;
    float* kl   = ws + off; off += 256 * 512;
    float* a2   = ws + off; off += (size_t)8 * 65536;
    float* z0   = ws + off; off += (size_t)8 * 65536;
    float* z1   = ws + off; off += (size_t)8 * 65536;
    float* xz   = ws + off; off += (size_t)8 * 65536;
    float* ta   = ws + off; off += (size_t)8 * 65536;
    float* tb   = ws + off; off += (size_t)8 * 65536;
    float* avb  = ws + off; off += (size_t)8 * 256 * 64;
    float* t2m  = ws + off; off += (size_t)8 * 256 * 64;
    float* bnn  = ws + off; off += 4 * 512;
    float* scr  = ws + off; off += 64;

    float* zf = nullptr;

    // ---- layer 2 (bottleneck path): only first 4 output rows are consumed ----
    run_layer_common(bott, 4, x2, ln2w, ln2b, qkv2w, N2, 9,
                     h, qkv, ql, kl, a2, z0, z1, xz, ta, tb, avb, t2m, scr, &zf, stream);
    stage_c<<<dim3(1, 8), 256, 0, stream>>>(qkv, kl, t2m, oh, 252);
    {
        int nrb = 1, thr = nrb * 512;
        conv_kernel<<<(thr + 255) / 256, 256, 0, stream>>>(qkv, cv2w, oh, 252, 4, N2);
    }
    l2out_kernel<<<8, 256, 0, stream>>>(oh, out2w, out2b, bott, om2, bnn);

    // ---- layer 1 (main path) ----
    run_layer_common(x1, 16384, bnn, ln1w, ln1b, qkv1w, N1, 65,
                     h, qkv, ql, kl, a2, z0, z1, xz, ta, tb, avb, t2m, scr, &zf, stream);
    stage_c<<<dim3(256, 8), 256, 0, stream>>>(qkv, kl, t2m, oh, 252);
    {
        int nrb = 16384 / 8, thr = nrb * 512;
        conv_kernel<<<(thr + 255) / 256, 256, 0, stream>>>(qkv, cv1w, oh, 252, 16384, N1);
    }
    dim3 g2(16384 / 128, 4);
    gemm_nt128<<<g2, 256, 0, stream>>>(oh + (size_t)252 * 512, out1w, (float*)d_out,
                                       512, 512, 512, 512, x1, out1b, om1);
}

// Round 5
// 3344.600 us; speedup vs baseline: 4.2375x; 1.2366x over previous
//
#include <hip/hip_runtime.h>
#include <math.h>

#define QKVLD 1536

// ---------------- LayerNorm with front zero-padding ----------------
__global__ __launch_bounds__(256) void ln_pad_kernel(
    const float* __restrict__ src1, int n1,
    const float* __restrict__ src2,
    const float* __restrict__ w, const float* __restrict__ b,
    float* __restrict__ h, int pad)
{
    int r = blockIdx.x;
    int tid = threadIdx.x;
    float* out = h + (size_t)r * 512;
    if (r < pad) { out[tid] = 0.f; out[tid + 256] = 0.f; return; }
    int i = r - pad;
    const float* src = (i < n1) ? (src1 + (size_t)i * 512)
                                : (src2 + (size_t)(i - n1) * 512);
    float x0 = src[tid], x1 = src[tid + 256];
    float s = x0 + x1, sq = x0 * x0 + x1 * x1;
#pragma unroll
    for (int o = 32; o >= 1; o >>= 1) { s += __shfl_xor(s, o); sq += __shfl_xor(sq, o); }
    __shared__ float rs[4], rq[4];
    int wid = tid >> 6, lane = tid & 63;
    if (lane == 0) { rs[wid] = s; rq[wid] = sq; }
    __syncthreads();
    s = rs[0] + rs[1] + rs[2] + rs[3];
    sq = rq[0] + rq[1] + rq[2] + rq[3];
    float mu = s * (1.f / 512.f);
    float var = sq * (1.f / 512.f) - mu * mu;
    float inv = rsqrtf(var + 1e-5f);
    out[tid]       = (x0 - mu) * inv * w[tid] + b[tid];
    out[tid + 256] = (x1 - mu) * inv * w[tid + 256] + b[tid + 256];
}

// ---------------- GEMM C[M x Nc] = A[M x K] @ B[Nc x K]^T, 128x128 tile, 8x8/thread ----
__global__ __launch_bounds__(256) void gemm_nt128(
    const float* __restrict__ A, const float* __restrict__ B, float* __restrict__ C,
    int K, int lda, int ldb, int ldc,
    const float* __restrict__ resid, const float* __restrict__ bias,
    const float* __restrict__ omega)
{
    __shared__ __align__(16) float As[16][128];
    __shared__ __align__(16) float Bs[16][128];
    int tid = threadIdx.x;
    int tx = tid & 15, ty = tid >> 4;
    int row0 = blockIdx.x * 128, col0 = blockIdx.y * 128;
    int lr = tid >> 1, lk = (tid & 1) << 3;   // each thread: 1 row, 8 consecutive k
    const float* Ap = A + (size_t)(row0 + lr) * lda + lk;
    const float* Bp = B + (size_t)(col0 + lr) * ldb + lk;
    float acc[8][8] = {};
    float4 a0 = *(const float4*)(Ap);
    float4 a1 = *(const float4*)(Ap + 4);
    float4 b0 = *(const float4*)(Bp);
    float4 b1 = *(const float4*)(Bp + 4);
    for (int kt = 0; kt < K; kt += 16) {
        __syncthreads();
        As[lk + 0][lr] = a0.x; As[lk + 1][lr] = a0.y; As[lk + 2][lr] = a0.z; As[lk + 3][lr] = a0.w;
        As[lk + 4][lr] = a1.x; As[lk + 5][lr] = a1.y; As[lk + 6][lr] = a1.z; As[lk + 7][lr] = a1.w;
        Bs[lk + 0][lr] = b0.x; Bs[lk + 1][lr] = b0.y; Bs[lk + 2][lr] = b0.z; Bs[lk + 3][lr] = b0.w;
        Bs[lk + 4][lr] = b1.x; Bs[lk + 5][lr] = b1.y; Bs[lk + 6][lr] = b1.z; Bs[lk + 7][lr] = b1.w;
        __syncthreads();
        if (kt + 16 < K) {
            a0 = *(const float4*)(Ap + kt + 16); a1 = *(const float4*)(Ap + kt + 20);
            b0 = *(const float4*)(Bp + kt + 16); b1 = *(const float4*)(Bp + kt + 20);
        }
#pragma unroll
        for (int k = 0; k < 16; ++k) {
            float4 av0 = *(const float4*)(&As[k][ty << 2]);
            float4 av1 = *(const float4*)(&As[k][64 + (ty << 2)]);
            float4 bv0 = *(const float4*)(&Bs[k][tx << 2]);
            float4 bv1 = *(const float4*)(&Bs[k][64 + (tx << 2)]);
            float a[8] = {av0.x, av0.y, av0.z, av0.w, av1.x, av1.y, av1.z, av1.w};
            float bb[8] = {bv0.x, bv0.y, bv0.z, bv0.w, bv1.x, bv1.y, bv1.z, bv1.w};
#pragma unroll
            for (int i = 0; i < 8; ++i)
#pragma unroll
                for (int j = 0; j < 8; ++j) acc[i][j] += a[i] * bb[j];
        }
    }
#pragma unroll
    for (int ih = 0; ih < 2; ++ih)
#pragma unroll
    for (int i = 0; i < 4; ++i) {
        int r = row0 + ih * 64 + (ty << 2) + i;
#pragma unroll
        for (int jh = 0; jh < 2; ++jh) {
            int c = col0 + jh * 64 + (tx << 2);
            float4 o = make_float4(acc[ih * 4 + i][jh * 4 + 0], acc[ih * 4 + i][jh * 4 + 1],
                                   acc[ih * 4 + i][jh * 4 + 2], acc[ih * 4 + i][jh * 4 + 3]);
            if (resid) {
                float om = omega[0];
                float4 rv = *(const float4*)(resid + (size_t)r * ldc + c);
                float4 bv = *(const float4*)(bias + c);
                o.x += om * rv.x + bv.x; o.y += om * rv.y + bv.y;
                o.z += om * rv.z + bv.z; o.w += om * rv.w + bv.w;
            }
            *(float4*)(C + (size_t)r * ldc + c) = o;
        }
    }
}

// ---------------- landmark means (q_l, k_l) ----------------
__global__ __launch_bounds__(256) void landmarks_kernel(
    const float* __restrict__ qkv, float* __restrict__ ql, float* __restrict__ kl, int l)
{
    int j = blockIdx.x;
    int tid = threadIdx.x;
    float inv = 1.f / (float)l;
    const float* base = qkv + (size_t)j * l * QKVLD;
    float sq0 = 0, sq1 = 0, sk0 = 0, sk1 = 0;
    for (int r = 0; r < l; ++r) {
        const float* row = base + (size_t)r * QKVLD;
        sq0 += row[tid]; sq1 += row[tid + 256];
        sk0 += row[512 + tid]; sk1 += row[512 + tid + 256];
    }
    ql[j * 512 + tid] = sq0 * inv; ql[j * 512 + tid + 256] = sq1 * inv;
    kl[j * 512 + tid] = sk0 * inv; kl[j * 512 + tid + 256] = sk1 * inv;
}

// ---------------- attn2 = softmax(0.125 * q_l @ k_l^T) per head ----------------
__global__ __launch_bounds__(256) void attn2_kernel(
    const float* __restrict__ ql, const float* __restrict__ kl, float* __restrict__ a2)
{
    int hh = blockIdx.y, i = blockIdx.x;
    int tid = threadIdx.x;
    __shared__ float qrow[64];
    __shared__ float red[4], red2[4];
    if (tid < 64) qrow[tid] = 0.125f * ql[i * 512 + hh * 64 + tid];
    __syncthreads();
    const float* krow = kl + (size_t)tid * 512 + hh * 64;
    float sc = 0.f;
#pragma unroll
    for (int d = 0; d < 64; ++d) sc += qrow[d] * krow[d];
    float m = sc;
#pragma unroll
    for (int o = 32; o >= 1; o >>= 1) m = fmaxf(m, __shfl_xor(m, o));
    int wid = tid >> 6, lane = tid & 63;
    if (lane == 0) red[wid] = m;
    __syncthreads();
    m = fmaxf(fmaxf(red[0], red[1]), fmaxf(red[2], red[3]));
    float p = __expf(sc - m);
    float s = p;
#pragma unroll
    for (int o = 32; o >= 1; o >>= 1) s += __shfl_xor(s, o);
    if (lane == 0) red2[wid] = s;
    __syncthreads();
    s = red2[0] + red2[1] + red2[2] + red2[3];
    a2[((size_t)hh * 256 + i) * 256 + tid] = p / s;
}

// ---------------- pinv: per-head max row/col sums ----------------
__global__ __launch_bounds__(256) void pinv_norms(const float* __restrict__ x, float* __restrict__ scr)
{
    int hh = blockIdx.x;
    const float* xh = x + ((size_t)hh << 16);
    int tid = threadIdx.x;
    float rs = 0.f, cs = 0.f;
    for (int j = 0; j < 256; ++j) rs += fabsf(xh[tid * 256 + j]);
    for (int i = 0; i < 256; ++i) cs += fabsf(xh[i * 256 + tid]);
#pragma unroll
    for (int o = 32; o >= 1; o >>= 1) { rs = fmaxf(rs, __shfl_xor(rs, o)); cs = fmaxf(cs, __shfl_xor(cs, o)); }
    __shared__ float r4[4], c4[4];
    int wid = tid >> 6, lane = tid & 63;
    if (lane == 0) { r4[wid] = rs; c4[wid] = cs; }
    __syncthreads();
    if (tid == 0) {
        scr[hh]     = fmaxf(fmaxf(r4[0], r4[1]), fmaxf(r4[2], r4[3]));
        scr[8 + hh] = fmaxf(fmaxf(c4[0], c4[1]), fmaxf(c4[2], c4[3]));
    }
}

// z0 = x^T / (col*row), col/row are GLOBAL maxima across heads
__global__ __launch_bounds__(256) void pinv_transpose(
    const float* __restrict__ x, const float* __restrict__ scr, float* __restrict__ z)
{
    float col = scr[0], row = scr[8];
#pragma unroll
    for (int k = 1; k < 8; ++k) { col = fmaxf(col, scr[k]); row = fmaxf(row, scr[8 + k]); }
    float s = 1.f / (col * row);
    int idx = blockIdx.x * 256 + threadIdx.x;
    int hh = idx >> 16, rem = idx & 65535, j = rem >> 8, i = rem & 255;
    z[idx] = x[((size_t)hh << 16) + (i << 8) + j] * s;
}

// ---------------- batched per-head 256x256: C = scl*(alpha*A - A@B) ----------------
// 32x64 tile, BK=64: 8 row-tiles x 4 col-tiles x 8 heads = 256 blocks (all CUs busy)
__global__ __launch_bounds__(256) void gemm256_pinv(
    const float* __restrict__ A, const float* __restrict__ B, float* __restrict__ C,
    float alpha, float scl)
{
    int hh = blockIdx.x >> 5, t = blockIdx.x & 31;
    int row0 = (t >> 2) << 5, col0 = (t & 3) << 6;
    const float* Ah = A + ((size_t)hh << 16);
    const float* Bh = B + ((size_t)hh << 16);
    float* Ch = C + ((size_t)hh << 16);
    int tid = threadIdx.x;
    __shared__ float As[64][33];                 // [k][row]
    __shared__ __align__(16) float Bs[64][68];   // [k][col], 68: 16B-aligned rows, conflict-spread
    int alr = tid & 31, alk = (tid >> 5) << 3;   // A loader: row alr, k = alk..alk+7
    int bbk = tid >> 4, bbc = (tid & 15) << 2;   // B loader: k = bbk+16j, col bbc..+3
    int ty = tid >> 4, tx = tid & 15;            // out: rows ty*2+{0,1}, cols tx*4..+3
    float acc[2][4] = {};
    float4 a0 = *(const float4*)(Ah + (size_t)(row0 + alr) * 256 + alk);
    float4 a1 = *(const float4*)(Ah + (size_t)(row0 + alr) * 256 + alk + 4);
    float4 bb0 = *(const float4*)(Bh + (size_t)(bbk +  0) * 256 + col0 + bbc);
    float4 bb1 = *(const float4*)(Bh + (size_t)(bbk + 16) * 256 + col0 + bbc);
    float4 bb2 = *(const float4*)(Bh + (size_t)(bbk + 32) * 256 + col0 + bbc);
    float4 bb3 = *(const float4*)(Bh + (size_t)(bbk + 48) * 256 + col0 + bbc);
    for (int kt = 0; kt < 256; kt += 64) {
        __syncthreads();
        As[alk + 0][alr] = a0.x; As[alk + 1][alr] = a0.y; As[alk + 2][alr] = a0.z; As[alk + 3][alr] = a0.w;
        As[alk + 4][alr] = a1.x; As[alk + 5][alr] = a1.y; As[alk + 6][alr] = a1.z; As[alk + 7][alr] = a1.w;
        *(float4*)(&Bs[bbk +  0][bbc]) = bb0;
        *(float4*)(&Bs[bbk + 16][bbc]) = bb1;
        *(float4*)(&Bs[bbk + 32][bbc]) = bb2;
        *(float4*)(&Bs[bbk + 48][bbc]) = bb3;
        __syncthreads();
        if (kt + 64 < 256) {
            int kn = kt + 64;
            a0 = *(const float4*)(Ah + (size_t)(row0 + alr) * 256 + kn + alk);
            a1 = *(const float4*)(Ah + (size_t)(row0 + alr) * 256 + kn + alk + 4);
            bb0 = *(const float4*)(Bh + (size_t)(kn + bbk +  0) * 256 + col0 + bbc);
            bb1 = *(const float4*)(Bh + (size_t)(kn + bbk + 16) * 256 + col0 + bbc);
            bb2 = *(const float4*)(Bh + (size_t)(kn + bbk + 32) * 256 + col0 + bbc);
            bb3 = *(const float4*)(Bh + (size_t)(kn + bbk + 48) * 256 + col0 + bbc);
        }
#pragma unroll
        for (int k = 0; k < 64; ++k) {
            float av0 = As[k][(ty << 1) + 0];
            float av1 = As[k][(ty << 1) + 1];
            float4 bv = *(const float4*)(&Bs[k][tx << 2]);
            acc[0][0] += av0 * bv.x; acc[0][1] += av0 * bv.y; acc[0][2] += av0 * bv.z; acc[0][3] += av0 * bv.w;
            acc[1][0] += av1 * bv.x; acc[1][1] += av1 * bv.y; acc[1][2] += av1 * bv.z; acc[1][3] += av1 * bv.w;
        }
    }
#pragma unroll
    for (int r = 0; r < 2; ++r) {
        int rr = row0 + (ty << 1) + r, cc = col0 + (tx << 2);
        float4 ae = *(const float4*)(Ah + (size_t)rr * 256 + cc);
        float4 o;
        o.x = scl * (alpha * ae.x - acc[r][0]);
        o.y = scl * (alpha * ae.y - acc[r][1]);
        o.z = scl * (alpha * ae.z - acc[r][2]);
        o.w = scl * (alpha * ae.w - acc[r][3]);
        *(float4*)(Ch + (size_t)rr * 256 + cc) = o;
    }
}

// ---------------- stage A (split-K): partial softmax(0.125 q_l @ k^T) @ v over a key slice ----
// grid (32, heads, 8 slices); 8 landmark rows/block; writes unnormalized acc + (m,l)
__global__ __launch_bounds__(256) void stage_a_slice(
    const float* __restrict__ qkv, const float* __restrict__ ql,
    float* __restrict__ pacc, float* __restrict__ pml, int N, int CS)
{
    int hh = blockIdx.y;
    int q0 = blockIdx.x * 8;
    int s  = blockIdx.z;
    int tid = threadIdx.x;
    int lane = tid & 63, wid = tid >> 6;
    __shared__ float qs[8][64];
    __shared__ __align__(16) float kv[128 * 68];
    __shared__ float ss[8][128];
    __shared__ __align__(16) float ps[8][128];
    __shared__ float mrow[8], srow[8], scalef[8];
    for (int t = tid; t < 512; t += 256) {
        int r = t >> 6, d = t & 63;
        qs[r][d] = 0.125f * ql[(q0 + r) * 512 + hh * 64 + d];
    }
    if (tid < 8) { mrow[tid] = -1e30f; srow[tid] = 0.f; }
    int d = tid & 63, sub = tid >> 6;
    float acc0 = 0.f, acc1 = 0.f;
    __syncthreads();
    int kb0 = s * CS * 128;
    for (int c = 0; c < CS; ++c) {
        int kb = kb0 + c * 128;
        if (kb >= N) break;
#pragma unroll
        for (int t = tid; t < 2048; t += 256) {
            int r = t >> 4, d4 = (t & 15) << 2;
            float4 vv = *(const float4*)(&qkv[(size_t)(kb + r) * QKVLD + 512 + hh * 64 + d4]);
            *(float4*)(&kv[r * 68 + d4]) = vv;
        }
        __syncthreads();
        {
            int j = tid & 127;
            int rb = (tid >> 7) * 4;
            float s0 = 0, s1 = 0, s2 = 0, s3 = 0;
#pragma unroll
            for (int dd4 = 0; dd4 < 64; dd4 += 4) {
                float4 kvv = *(const float4*)(&kv[j * 68 + dd4]);
                float4 qv0 = *(const float4*)(&qs[rb + 0][dd4]);
                float4 qv1 = *(const float4*)(&qs[rb + 1][dd4]);
                float4 qv2 = *(const float4*)(&qs[rb + 2][dd4]);
                float4 qv3 = *(const float4*)(&qs[rb + 3][dd4]);
                s0 += qv0.x * kvv.x + qv0.y * kvv.y + qv0.z * kvv.z + qv0.w * kvv.w;
                s1 += qv1.x * kvv.x + qv1.y * kvv.y + qv1.z * kvv.z + qv1.w * kvv.w;
                s2 += qv2.x * kvv.x + qv2.y * kvv.y + qv2.z * kvv.z + qv2.w * kvv.w;
                s3 += qv3.x * kvv.x + qv3.y * kvv.y + qv3.z * kvv.z + qv3.w * kvv.w;
            }
            ss[rb + 0][j] = s0; ss[rb + 1][j] = s1; ss[rb + 2][j] = s2; ss[rb + 3][j] = s3;
        }
        __syncthreads();
#pragma unroll
        for (int rr = 0; rr < 2; ++rr) {
            int row = wid + rr * 4;
            float a = ss[row][lane], b2 = ss[row][lane + 64];
            float mx = fmaxf(a, b2);
#pragma unroll
            for (int o = 32; o >= 1; o >>= 1) mx = fmaxf(mx, __shfl_xor(mx, o));
            float newm = fmaxf(mrow[row], mx);
            float pa = __expf(a - newm), pb = __expf(b2 - newm);
            ps[row][lane] = pa; ps[row][lane + 64] = pb;
            float sum = pa + pb;
#pragma unroll
            for (int o = 32; o >= 1; o >>= 1) sum += __shfl_xor(sum, o);
            if (lane == 0) {
                float f = __expf(mrow[row] - newm);
                scalef[row] = f;
                srow[row] = srow[row] * f + sum;
                mrow[row] = newm;
            }
        }
        __syncthreads();
        acc0 *= scalef[sub];
        acc1 *= scalef[sub + 4];
#pragma unroll
        for (int t = tid; t < 2048; t += 256) {
            int r = t >> 4, d4 = (t & 15) << 2;
            float4 vv = *(const float4*)(&qkv[(size_t)(kb + r) * QKVLD + 1024 + hh * 64 + d4]);
            *(float4*)(&kv[r * 68 + d4]) = vv;
        }
        __syncthreads();
#pragma unroll 8
        for (int j = 0; j < 128; j += 4) {
            float4 p0 = *(const float4*)(&ps[sub][j]);
            float4 p1 = *(const float4*)(&ps[sub + 4][j]);
            float v0 = kv[(j + 0) * 68 + d];
            float v1 = kv[(j + 1) * 68 + d];
            float v2 = kv[(j + 2) * 68 + d];
            float v3 = kv[(j + 3) * 68 + d];
            acc0 += p0.x * v0 + p0.y * v1 + p0.z * v2 + p0.w * v3;
            acc1 += p1.x * v0 + p1.y * v1 + p1.z * v2 + p1.w * v3;
        }
        __syncthreads();
    }
    size_t base0 = (((size_t)hh * 256 + q0 + sub) * 8 + s) * 64 + d;
    size_t base1 = (((size_t)hh * 256 + q0 + sub + 4) * 8 + s) * 64 + d;
    pacc[base0] = acc0;
    pacc[base1] = acc1;
    if (tid < 8) {
        size_t mb = (((size_t)hh * 256 + q0 + tid) * 8 + s) * 2;
        pml[mb] = mrow[tid]; pml[mb + 1] = srow[tid];
    }
}

// ---------------- stage A combine: av = sum_s acc_s e^{m_s-M} / sum_s l_s e^{m_s-M} ----------
__global__ __launch_bounds__(256) void stage_a_combine(
    const float* __restrict__ pacc, const float* __restrict__ pml, float* __restrict__ av)
{
    int hh = blockIdx.y;
    int tid = threadIdx.x;
    int row = blockIdx.x * 4 + (tid >> 6);
    int d = tid & 63;
    size_t rb = (size_t)hh * 256 + row;
    float M = -1e30f;
#pragma unroll
    for (int s = 0; s < 8; ++s) M = fmaxf(M, pml[(rb * 8 + s) * 2]);
    float L = 0.f, a = 0.f;
#pragma unroll
    for (int s = 0; s < 8; ++s) {
        float ms = pml[(rb * 8 + s) * 2];
        float ls = pml[(rb * 8 + s) * 2 + 1];
        float f = __expf(ms - M);
        L += ls * f;
        a += pacc[(rb * 8 + s) * 64 + d] * f;
    }
    av[rb * 64 + d] = a / L;
}

// ---------------- t2m = attn2_inv @ av (per head, 256x256 @ 256x64) ----------------
__global__ __launch_bounds__(256) void zmm_kernel(
    const float* __restrict__ Z, const float* __restrict__ av, float* __restrict__ t2m)
{
    int hh = blockIdx.y;
    int row0 = blockIdx.x * 64;
    int tid = threadIdx.x;
    int r = tid >> 2, q = tid & 3;
    __shared__ float zs[64][65];
    __shared__ float vs[64][65];
    float acc[16] = {};
#pragma unroll 4
    for (int kc = 0; kc < 4; ++kc) {
        __syncthreads();
        for (int t = tid; t < 4096; t += 256) {
            int a = t >> 6, dd = t & 63;
            zs[a][dd] = Z[((size_t)hh << 16) + (row0 + a) * 256 + kc * 64 + dd];
            vs[a][dd] = av[((size_t)hh * 256 + kc * 64 + a) * 64 + dd];
        }
        __syncthreads();
#pragma unroll
        for (int k = 0; k < 64; ++k) {
            float z = zs[r][k];
#pragma unroll
            for (int dd = 0; dd < 16; ++dd) acc[dd] += z * vs[k][q * 16 + dd];
        }
    }
    float* op = t2m + ((size_t)hh * 256 + row0 + r) * 64 + q * 16;
    *(float4*)(op + 0)  = make_float4(acc[0], acc[1], acc[2], acc[3]);
    *(float4*)(op + 4)  = make_float4(acc[4], acc[5], acc[6], acc[7]);
    *(float4*)(op + 8)  = make_float4(acc[8], acc[9], acc[10], acc[11]);
    *(float4*)(op + 12) = make_float4(acc[12], acc[13], acc[14], acc[15]);
}

// ---------------- stage C (flash-style, spill-free): oh = softmax(0.125 q @ kl^T) @ t2m ----
__global__ __launch_bounds__(256) void stage_c(
    const float* __restrict__ qkv, const float* __restrict__ kl,
    const float* __restrict__ t2m, float* __restrict__ oh, int r0)
{
    int hh = blockIdx.y;
    int row0 = r0 + blockIdx.x * 64;
    int tid = threadIdx.x;
    int r = tid >> 2, q = tid & 3;          // 4 threads per row (same wave: shfl_xor 1,2)
    __shared__ float qs[64][65];
    __shared__ float cs[64][65];            // time-shared: kl chunk, then t2m chunk
    __shared__ float pl[64][65];
    for (int t = tid; t < 4096; t += 256) {
        int rr = t >> 6, dd = t & 63;
        qs[rr][dd] = 0.125f * qkv[(size_t)(row0 + rr) * QKVLD + hh * 64 + dd];
    }
    float m = -1e30f, l = 0.f;
    float acc[16] = {};
    for (int c = 0; c < 4; ++c) {
        __syncthreads();                    // prev PV reads of cs done
        for (int t = tid; t < 4096; t += 256) {
            int jl = t >> 6, dd = t & 63;
            cs[jl][dd] = kl[(c * 64 + jl) * 512 + hh * 64 + dd];
        }
        __syncthreads();
        float s[16];
        float mx = -1e30f;
#pragma unroll
        for (int jj = 0; jj < 16; ++jj) {
            int jl = q * 16 + jj;
            float sv = 0.f;
#pragma unroll
            for (int dd = 0; dd < 64; ++dd) sv += qs[r][dd] * cs[jl][dd];
            s[jj] = sv;
            mx = fmaxf(mx, sv);
        }
        mx = fmaxf(mx, __shfl_xor(mx, 1));
        mx = fmaxf(mx, __shfl_xor(mx, 2));
        float mn = fmaxf(m, mx);
        float scale = __expf(m - mn);
        m = mn;
        float psum = 0.f;
#pragma unroll
        for (int jj = 0; jj < 16; ++jj) { s[jj] = __expf(s[jj] - mn); psum += s[jj]; }
        psum += __shfl_xor(psum, 1);
        psum += __shfl_xor(psum, 2);
        l = l * scale + psum;
#pragma unroll
        for (int i = 0; i < 16; ++i) acc[i] *= scale;
#pragma unroll
        for (int jj = 0; jj < 16; ++jj) pl[r][q * 16 + jj] = s[jj];
        __syncthreads();                    // pl ready; cs reads (scores) done
        for (int t = tid; t < 4096; t += 256) {
            int jl = t >> 6, dd = t & 63;
            cs[jl][dd] = t2m[((size_t)hh * 256 + c * 64 + jl) * 64 + dd];
        }
        __syncthreads();
#pragma unroll
        for (int j = 0; j < 64; ++j) {
            float p = pl[r][j];
#pragma unroll
            for (int i = 0; i < 16; ++i) acc[i] += p * cs[j][q * 16 + i];
        }
    }
    float invl = 1.f / l;
    float* op = oh + (size_t)(row0 + r) * 512 + hh * 64 + q * 16;
#pragma unroll
    for (int v4 = 0; v4 < 4; ++v4)
        *(float4*)(op + v4 * 4) = make_float4(acc[v4 * 4 + 0] * invl, acc[v4 * 4 + 1] * invl,
                                              acc[v4 * 4 + 2] * invl, acc[v4 * 4 + 3] * invl);
}

// ---------------- depthwise conv (k=33): 8 output rows per thread, sliding window ----------------
__global__ __launch_bounds__(256) void conv_kernel(
    const float* __restrict__ qkv, const float* __restrict__ w,
    float* __restrict__ oh, int r0, int nrows, int N)
{
    int idx = blockIdx.x * 256 + threadIdx.x;
    int nrb = (nrows + 7) >> 3;
    if (idx >= nrb * 512) return;
    int rb = idx >> 9, c = idx & 511;
    int hh = c >> 6;
    int g0 = r0 + rb * 8;
    float wr[33];
#pragma unroll
    for (int k = 0; k < 33; ++k) wr[k] = w[hh * 33 + k];
    float acc[8] = {};
#pragma unroll
    for (int t = 0; t < 41; ++t) {
        int row = g0 + t - 16;
        float v = (row >= 0 && row < N) ? qkv[(size_t)row * QKVLD + 1024 + c] : 0.f;
#pragma unroll
        for (int i = 0; i < 8; ++i) {
            int k = t - i;
            if (k >= 0 && k < 33) acc[i] += wr[k] * v;
        }
    }
#pragma unroll
    for (int i = 0; i < 8; ++i) {
        int g = g0 + i;
        if (g < r0 + nrows) oh[(size_t)g * 512 + c] += acc[i];
    }
}

// ---------------- layer2 final projection: 4 rows only ----------------
__global__ __launch_bounds__(256) void l2out_kernel(
    const float* __restrict__ oh, const float* __restrict__ W,
    const float* __restrict__ bias, const float* __restrict__ bott,
    const float* __restrict__ omega, float* __restrict__ bn_new)
{
    int idx = blockIdx.x * 256 + threadIdx.x;  // 4*512
    int i = idx >> 9, j = idx & 511;
    float acc = bias[j];
    const float* ar = oh + (size_t)(252 + i) * 512;
    const float* wr = W + (size_t)j * 512;
    for (int k = 0; k < 512; ++k) acc += ar[k] * wr[k];
    bn_new[idx] = bott[idx] * omega[0] + acc;
}

// ---------------- host ----------------
static void run_layer_common(const float* src1, int n1, const float* src2,
                             const float* lnw, const float* lnb, const float* qkvw,
                             int N, int l,
                             float* h, float* qkv, float* ql, float* kl,
                             float* a2, float* z0, float* z1, float* xz,
                             float* ta, float* tb, float* avb, float* t2m,
                             float* pacc, float* pml,
                             float* scr, float** z_final, hipStream_t stream)
{
    ln_pad_kernel<<<N, 256, 0, stream>>>(src1, n1, src2, lnw, lnb, h, 252);
    dim3 g1(N / 128, 12);
    gemm_nt128<<<g1, 256, 0, stream>>>(h, qkvw, qkv, 512, 512, 512, QKVLD, nullptr, nullptr, nullptr);
    landmarks_kernel<<<256, 256, 0, stream>>>(qkv, ql, kl, l);
    attn2_kernel<<<dim3(256, 8), 256, 0, stream>>>(ql, kl, a2);
    pinv_norms<<<8, 256, 0, stream>>>(a2, scr);
    pinv_transpose<<<2048, 256, 0, stream>>>(a2, scr, z0);
    float* zc = z0; float* zn = z1;
    for (int it = 0; it < 6; ++it) {
        gemm256_pinv<<<256, 256, 0, stream>>>(a2, zc, xz, 0.f, -1.f);   // xz = a2@z
        gemm256_pinv<<<256, 256, 0, stream>>>(xz, xz, ta, 7.f, 1.f);    // ta = 7xz - xz@xz
        gemm256_pinv<<<256, 256, 0, stream>>>(xz, ta, tb, 15.f, 1.f);   // tb = 15xz - xz@ta
        gemm256_pinv<<<256, 256, 0, stream>>>(zc, tb, zn, 13.f, 0.25f); // z  = .25(13z - z@tb)
        float* tmp = zc; zc = zn; zn = tmp;
    }
    int CS = (N / 128 + 7) / 8;
    stage_a_slice<<<dim3(32, 8, 8), 256, 0, stream>>>(qkv, ql, pacc, pml, N, CS);
    stage_a_combine<<<dim3(64, 8), 256, 0, stream>>>(pacc, pml, avb);
    zmm_kernel<<<dim3(4, 8), 256, 0, stream>>>(zc, avb, t2m);
    *z_final = zc;
}

extern "C" void kernel_launch(void* const* d_in, const int* in_sizes, int n_in,
                              void* d_out, int out_size, void* d_ws, size_t ws_size,
                              hipStream_t stream) {
    (void)in_sizes; (void)n_in; (void)out_size; (void)ws_size;
    const float* x1    = (const float*)d_in[0];
    const float* x2    = (const float*)d_in[1];
    const float* bott  = (const float*)d_in[2];
    const float* ln1w  = (const float*)d_in[3];
    const float* ln1b  = (const float*)d_in[4];
    const float* qkv1w = (const float*)d_in[5];
    const float* out1w = (const float*)d_in[6];
    const float* out1b = (const float*)d_in[7];
    const float* cv1w  = (const float*)d_in[8];
    const float* om1   = (const float*)d_in[9];
    const float* ln2w  = (const float*)d_in[10];
    const float* ln2b  = (const float*)d_in[11];
    const float* qkv2w = (const float*)d_in[12];
    const float* out2w = (const float*)d_in[13];
    const float* out2b = (const float*)d_in[14];
    const float* cv2w  = (const float*)d_in[15];
    const float* om2   = (const float*)d_in[16];

    const int N1 = 16640, N2 = 2304;
    float* ws = (float*)d_ws;
    size_t off = 0;
    float* h    = ws + off; off += (size_t)N1 * 512;   // aliased: LN output, then attention output (oh)
    float* oh   = h;                                   // h is dead after the QKV GEMM
    float* qkv  = ws + off; off += (size_t)N1 * 1536;
    float* ql   = ws + off; off += 256 * 512;
    float* kl   = ws + off; off += 256 * 512;
    float* a2   = ws + off; off += (size_t)8 * 65536;
    float* z0   = ws + off; off += (size_t)8 * 65536;
    float* z1   = ws + off; off += (size_t)8 * 65536;
    float* xz   = ws + off; off += (size_t)8 * 65536;
    float* ta   = ws + off; off += (size_t)8 * 65536;
    float* tb   = ws + off; off += (size_t)8 * 65536;
    float* avb  = ws + off; off += (size_t)8 * 256 * 64;
    float* t2m  = ws + off; off += (size_t)8 * 256 * 64;
    float* pacc = ws + off; off += (size_t)8 * 256 * 8 * 64;
    float* pml  = ws + off; off += (size_t)8 * 256 * 8 * 2;
    float* bnn  = ws + off; off += 4 * 512;
    float* scr  = ws + off; off += 64;

    float* zf = nullptr;

    // ---- layer 2 (bottleneck path): only first 4 output rows are consumed ----
    run_layer_common(bott, 4, x2, ln2w, ln2b, qkv2w, N2, 9,
                     h, qkv, ql, kl, a2, z0, z1, xz, ta, tb, avb, t2m, pacc, pml, scr, &zf, stream);
    stage_c<<<dim3(1, 8), 256, 0, stream>>>(qkv, kl, t2m, oh, 252);
    conv_kernel<<<2, 256, 0, stream>>>(qkv, cv2w, oh, 252, 4, N2);
    l2out_kernel<<<8, 256, 0, stream>>>(oh, out2w, out2b, bott, om2, bnn);

    // ---- layer 1 (main path) ----
    run_layer_common(x1, 16384, bnn, ln1w, ln1b, qkv1w, N1, 65,
                     h, qkv, ql, kl, a2, z0, z1, xz, ta, tb, avb, t2m, pacc, pml, scr, &zf, stream);
    stage_c<<<dim3(256, 8), 256, 0, stream>>>(qkv, kl, t2m, oh, 252);
    {
        int nrb = 16384 / 8, thr = nrb * 512;
        conv_kernel<<<(thr + 255) / 256, 256, 0, stream>>>(qkv, cv1w, oh, 252, 16384, N1);
    }
    dim3 g2(16384 / 128, 4);
    gemm_nt128<<<g2, 256, 0, stream>>>(oh + (size_t)252 * 512, out1w, (float*)d_out,
                                       512, 512, 512, 512, x1, out1b, om1);
}